// Round 2
// baseline (312.757 us; speedup 1.0000x reference)
//
#include <hip/hip_runtime.h>

typedef __bf16 bf16;
typedef __attribute__((ext_vector_type(8))) __bf16 bf16x8;
typedef __attribute__((ext_vector_type(4))) __bf16 bf16x4;
typedef __attribute__((ext_vector_type(4))) float f32x4;

#define AS1C(p) ((const __attribute__((address_space(1))) void*)(p))
#define AS3(p)  ((__attribute__((address_space(3))) void*)(p))

// ---------------- cast f32 -> bf16, vectorized ----------------
__global__ void castk(const float* __restrict__ in, bf16* __restrict__ out, long n) {
  long i = ((long)blockIdx.x * blockDim.x + threadIdx.x) * 4;
  if (i >= n) return;
  f32x4 v = *reinterpret_cast<const f32x4*>(in + i);
  bf16x4 o;
  o[0] = (bf16)v[0]; o[1] = (bf16)v[1]; o[2] = (bf16)v[2]; o[3] = (bf16)v[3];
  *reinterpret_cast<bf16x4*>(out + i) = o;
}

// ---------------- GEMM: C = A * BT^T + bias (unchanged from r1) ----------------
template<int EPI>
__global__ __launch_bounds__(256, 2)
void gemm_bt(const bf16* __restrict__ A, const bf16* __restrict__ BT,
             const float* __restrict__ bias, void* __restrict__ Cout,
             int M, int N, int K) {
  __shared__ bf16 As[128 * 64];
  __shared__ bf16 Bs[128 * 64];
  const int tid = threadIdx.x;
  const int lane = tid & 63;
  const int w = tid >> 6;
  const int wm = w >> 1, wn = w & 1;
  const int row0 = blockIdx.y * 128, col0 = blockIdx.x * 128;

  f32x4 acc[4][4] = {};

  const int srow = tid >> 3;
  const int scb = ((tid & 7) << 4) ^ ((srow & 7) << 4);
  const long aoff = (long)(row0 + srow) * K + (scb >> 1);
  const long boff = (long)(col0 + srow) * K + (scb >> 1);

  for (int k0 = 0; k0 < K; k0 += 64) {
    #pragma unroll
    for (int i = 0; i < 4; ++i) {
      __builtin_amdgcn_global_load_lds(AS1C(A + aoff + (long)i * 32 * K + k0),
                                       AS3((char*)As + i * 4096 + w * 1024), 16, 0, 0);
      __builtin_amdgcn_global_load_lds(AS1C(BT + boff + (long)i * 32 * K + k0),
                                       AS3((char*)Bs + i * 4096 + w * 1024), 16, 0, 0);
    }
    __syncthreads();
    #pragma unroll
    for (int kf = 0; kf < 2; ++kf) {
      bf16x8 af[4], bfr[4];
      #pragma unroll
      for (int m = 0; m < 4; ++m) {
        int r = wm * 64 + m * 16 + (lane & 15);
        int cb = (kf * 64 + ((lane >> 4) << 4)) ^ ((r & 7) << 4);
        af[m] = *reinterpret_cast<const bf16x8*>((const char*)As + r * 128 + cb);
      }
      #pragma unroll
      for (int n = 0; n < 4; ++n) {
        int r = wn * 64 + n * 16 + (lane & 15);
        int cb = (kf * 64 + ((lane >> 4) << 4)) ^ ((r & 7) << 4);
        bfr[n] = *reinterpret_cast<const bf16x8*>((const char*)Bs + r * 128 + cb);
      }
      #pragma unroll
      for (int m = 0; m < 4; ++m)
        #pragma unroll
        for (int n = 0; n < 4; ++n)
          acc[m][n] = __builtin_amdgcn_mfma_f32_16x16x32_bf16(af[m], bfr[n], acc[m][n], 0, 0, 0);
    }
    __syncthreads();
  }

  #pragma unroll
  for (int m = 0; m < 4; ++m) {
    #pragma unroll
    for (int n = 0; n < 4; ++n) {
      #pragma unroll
      for (int r = 0; r < 4; ++r) {
        int grow = row0 + wm * 64 + m * 16 + ((lane >> 4) << 2) + r;
        int gcol = col0 + wn * 64 + n * 16 + (lane & 15);
        float v = acc[m][n][r] + bias[gcol];
        if constexpr (EPI == 0) {
          reinterpret_cast<float*>(Cout)[(long)grow * N + gcol] = v;
        } else {
          int t = gcol >> 10;
          int h = (gcol >> 6) & 15;
          int hd = gcol & 63;
          int bb = grow >> 11;
          int ll = grow & 2047;
          long bh = bb * 16 + h;
          bf16* base = reinterpret_cast<bf16*>(Cout);
          if (t == 0) {
            base[(bh * 2048 + ll) * 64 + hd] = (bf16)(v * 0.125f);  // Q, scale folded
          } else if (t == 1) {
            base[8388608 + (bh * 2048 + ll) * 64 + hd] = (bf16)v;   // K
          } else {
            base[16777216 + (bh * 64 + hd) * 2048 + ll] = (bf16)v;  // V^T
          }
        }
      }
    }
  }
}

// ---------------- causal flash attention v2 ----------------
// Q,K: [bh][2048][64] bf16 (Q pre-scaled). VT: [bh][64][2048] bf16.
// Block: 128 Q-rows, 4 waves x 32 rows. KV tiles of 64, double-buffered LDS.
// One barrier per KV tile; stage(kt+1) issued before compute(kt) so HBM/L2
// latency hides under QK+softmax+PV (2-phase T3 pattern).
__global__ __launch_bounds__(256, 3)
void attn_fwd(const bf16* __restrict__ Qg, const bf16* __restrict__ Kg,
              const bf16* __restrict__ VTg, bf16* __restrict__ Og) {
  __shared__ bf16 Ks[2][64 * 64];
  __shared__ bf16 Vs[2][64 * 64];
  __shared__ bf16 Ps[4][32 * 64];
  const int tid = threadIdx.x, lane = tid & 63, w = tid >> 6;
  const int qi = (int)gridDim.x - 1 - (int)blockIdx.x;  // heavy blocks first
  const int q0 = qi * 128;
  const int bh = blockIdx.y;
  const int bb = bh >> 4, h = bh & 15;
  const long base = (long)bh * (2048 * 64);
  const int qw = q0 + w * 32;

  // Q fragments: 2 m-frags x 2 k-halves
  bf16x8 qf[2][2];
  #pragma unroll
  for (int m = 0; m < 2; ++m) {
    int qrow = qw + m * 16 + (lane & 15);
    qf[m][0] = *reinterpret_cast<const bf16x8*>(Qg + base + (long)qrow * 64 + ((lane >> 4) << 3));
    qf[m][1] = *reinterpret_cast<const bf16x8*>(Qg + base + (long)qrow * 64 + 32 + ((lane >> 4) << 3));
  }

  f32x4 accO[2][4] = {};
  float mrow[2][4], lrow[2][4];
  #pragma unroll
  for (int m = 0; m < 2; ++m)
    #pragma unroll
    for (int r = 0; r < 4; ++r) { mrow[m][r] = -1e30f; lrow[m][r] = 0.f; }

  const int srow = tid >> 3;
  const int scb = ((tid & 7) << 4) ^ ((srow & 7) << 4);
  const int nt = 2 * qi + 2;                 // KV tiles for this block
  const int ntw = ((qw + 31) >> 6) + 1;      // tiles this wave actually computes

  auto stage = [&](int kt, int buf) {
    #pragma unroll
    for (int i = 0; i < 2; ++i) {
      __builtin_amdgcn_global_load_lds(
          AS1C(Kg + base + (long)(kt * 64 + i * 32 + srow) * 64 + (scb >> 1)),
          AS3((char*)&Ks[buf][0] + i * 4096 + w * 1024), 16, 0, 0);
      __builtin_amdgcn_global_load_lds(
          AS1C(VTg + base + (long)(i * 32 + srow) * 2048 + kt * 64 + (scb >> 1)),
          AS3((char*)&Vs[buf][0] + i * 4096 + w * 1024), 16, 0, 0);
    }
  };

  stage(0, 0);

  for (int kt = 0; kt < nt; ++kt) {
    const int cur = kt & 1;
    __syncthreads();                          // stage(kt) complete; prev reads done
    if (kt + 1 < nt) stage(kt + 1, cur ^ 1);  // prefetch, in flight across compute
    if (kt >= ntw) continue;                  // fully-masked for this wave

    const char* Kb = (const char*)&Ks[cur][0];
    const char* Vb = (const char*)&Vs[cur][0];

    // S = Q K^T
    f32x4 s[2][4] = {};
    #pragma unroll
    for (int kf = 0; kf < 2; ++kf) {
      #pragma unroll
      for (int n = 0; n < 4; ++n) {
        int r = n * 16 + (lane & 15);
        int cb = (kf * 64 + ((lane >> 4) << 4)) ^ ((r & 7) << 4);
        bf16x8 kb = *reinterpret_cast<const bf16x8*>(Kb + r * 128 + cb);
        s[0][n] = __builtin_amdgcn_mfma_f32_16x16x32_bf16(qf[0][kf], kb, s[0][n], 0, 0, 0);
        s[1][n] = __builtin_amdgcn_mfma_f32_16x16x32_bf16(qf[1][kf], kb, s[1][n], 0, 0, 0);
      }
    }

    // causal mask (only tiles that touch the diagonal of this wave's rows)
    if (kt * 64 + 63 > qw) {
      #pragma unroll
      for (int m = 0; m < 2; ++m) {
        #pragma unroll
        for (int n = 0; n < 4; ++n) {
          int kvl = kt * 64 + n * 16 + (lane & 15);
          #pragma unroll
          for (int r = 0; r < 4; ++r) {
            int ql = qw + m * 16 + ((lane >> 4) << 2) + r;
            if (kvl > ql) s[m][n][r] = -1e30f;
          }
        }
      }
    }

    // online softmax (row = 16 lanes sharing lane>>4)
    #pragma unroll
    for (int m = 0; m < 2; ++m) {
      #pragma unroll
      for (int r = 0; r < 4; ++r) {
        float vm = fmaxf(fmaxf(s[m][0][r], s[m][1][r]), fmaxf(s[m][2][r], s[m][3][r]));
        #pragma unroll
        for (int off = 1; off < 16; off <<= 1) vm = fmaxf(vm, __shfl_xor(vm, off));
        float mnew = fmaxf(mrow[m][r], vm);
        float fac = __expf(mrow[m][r] - mnew);
        mrow[m][r] = mnew;
        float ps = 0.f;
        #pragma unroll
        for (int n = 0; n < 4; ++n) {
          float p = __expf(s[m][n][r] - mnew);
          s[m][n][r] = p;
          ps += p;
        }
        #pragma unroll
        for (int off = 1; off < 16; off <<= 1) ps += __shfl_xor(ps, off);
        lrow[m][r] = lrow[m][r] * fac + ps;
        #pragma unroll
        for (int n = 0; n < 4; ++n) accO[m][n][r] *= fac;
      }
    }

    // P: C-layout regs -> A-fragment layout via per-wave swizzled LDS
    #pragma unroll
    for (int m = 0; m < 2; ++m) {
      #pragma unroll
      for (int n = 0; n < 4; ++n) {
        #pragma unroll
        for (int r = 0; r < 4; ++r) {
          int prow = m * 16 + ((lane >> 4) << 2) + r;
          int pcb = ((n * 16 + (lane & 15)) << 1) ^ ((prow & 7) << 4);
          *reinterpret_cast<bf16*>((char*)&Ps[w][0] + prow * 128 + pcb) = (bf16)s[m][n][r];
        }
      }
    }
    asm volatile("s_waitcnt lgkmcnt(0)" ::: "memory");
    __builtin_amdgcn_sched_barrier(0);

    // O += P * V
    #pragma unroll
    for (int kf = 0; kf < 2; ++kf) {
      bf16x8 pa[2];
      #pragma unroll
      for (int m = 0; m < 2; ++m) {
        int prow = m * 16 + (lane & 15);
        int pcb = (kf * 64 + ((lane >> 4) << 4)) ^ ((prow & 7) << 4);
        pa[m] = *reinterpret_cast<const bf16x8*>((const char*)&Ps[w][0] + prow * 128 + pcb);
      }
      #pragma unroll
      for (int n = 0; n < 4; ++n) {
        int vrow = n * 16 + (lane & 15);
        int vcb = (kf * 64 + ((lane >> 4) << 4)) ^ ((vrow & 7) << 4);
        bf16x8 vb = *reinterpret_cast<const bf16x8*>(Vb + vrow * 128 + vcb);
        accO[0][n] = __builtin_amdgcn_mfma_f32_16x16x32_bf16(pa[0], vb, accO[0][n], 0, 0, 0);
        accO[1][n] = __builtin_amdgcn_mfma_f32_16x16x32_bf16(pa[1], vb, accO[1][n], 0, 0, 0);
      }
    }
  }

  // normalize + store O[b*2048+l][h*64+hd]
  #pragma unroll
  for (int m = 0; m < 2; ++m) {
    #pragma unroll
    for (int n = 0; n < 4; ++n) {
      #pragma unroll
      for (int r = 0; r < 4; ++r) {
        int ql = qw + m * 16 + ((lane >> 4) << 2) + r;
        int col = h * 64 + n * 16 + (lane & 15);
        float v = accO[m][n][r] / lrow[m][r];
        Og[((long)(bb * 2048 + ql)) * 1024 + col] = (bf16)v;
      }
    }
  }
}

// ---------------- launch ----------------
extern "C" void kernel_launch(void* const* d_in, const int* in_sizes, int n_in,
                              void* d_out, int out_size, void* d_ws, size_t ws_size,
                              hipStream_t stream) {
  (void)in_sizes; (void)n_in; (void)out_size; (void)ws_size;
  const float* x     = (const float*)d_in[0];
  const float* Wqkv  = (const float*)d_in[3];
  const float* bqkv  = (const float*)d_in[4];
  const float* Wproj = (const float*)d_in[5];
  const float* bproj = (const float*)d_in[6];

  bf16* xb     = (bf16*)d_ws;              // 8192*1024
  bf16* Wqkvb  = xb + 8388608;             // 3072*1024
  bf16* Wprojb = Wqkvb + 3145728;          // 1024*1024
  bf16* Qb     = Wprojb + 1048576;         // Q | K | VT : 3 * 8388608
  bf16* Ob     = Qb + 3 * 8388608;         // 8192*1024

  castk<<<8192, 256, 0, stream>>>(x, xb, 8388608);
  castk<<<3072, 256, 0, stream>>>(Wqkv, Wqkvb, 3145728);
  castk<<<1024, 256, 0, stream>>>(Wproj, Wprojb, 1048576);

  // QKV GEMM: M=8192, N=3072, K=1024, scatter epilogue
  gemm_bt<1><<<dim3(24, 64), 256, 0, stream>>>(xb, Wqkvb, bqkv, (void*)Qb, 8192, 3072, 1024);

  // attention: 16 q-blocks (128 rows) x 64 (b,h)
  attn_fwd<<<dim3(16, 64), 256, 0, stream>>>(Qb, Qb + 8388608, Qb + 16777216, Ob);

  // proj GEMM: M=8192, N=1024, K=1024 -> f32 d_out
  gemm_bt<0><<<dim3(8, 64), 256, 0, stream>>>(Ob, Wprojb, bproj, d_out, 8192, 1024, 1024);
}

// Round 3
// 201.582 us; speedup vs baseline: 1.5515x; 1.5515x over previous
//
#include <hip/hip_runtime.h>

typedef __bf16 bf16;
typedef __attribute__((ext_vector_type(8))) __bf16 bf16x8;
typedef __attribute__((ext_vector_type(4))) __bf16 bf16x4;
typedef __attribute__((ext_vector_type(4))) float f32x4;
typedef __attribute__((ext_vector_type(4))) short short4v;

#define AS1C(p) ((const __attribute__((address_space(1))) void*)(p))
#define AS3(p)  ((__attribute__((address_space(3))) void*)(p))

// K=16 bf16 MFMA for PV (P^T frag is already in B-layout: zero cross-lane movement)
static __device__ __forceinline__ f32x4 pv_mfma(bf16x4 a, bf16x4 b, f32x4 c) {
#if __has_builtin(__builtin_amdgcn_mfma_f32_16x16x16bf16_1k)
  return __builtin_amdgcn_mfma_f32_16x16x16bf16_1k(
      __builtin_bit_cast(short4v, a), __builtin_bit_cast(short4v, b), c, 0, 0, 0);
#else
  f32x4 d = c;
  asm("v_mfma_f32_16x16x16_bf16 %0, %1, %2, %0" : "+v"(d) : "v"(a), "v"(b));
  return d;
#endif
}

// ---------------- cast f32 -> bf16, vectorized ----------------
__global__ void castk(const float* __restrict__ in, bf16* __restrict__ out, long n) {
  long i = ((long)blockIdx.x * blockDim.x + threadIdx.x) * 4;
  if (i >= n) return;
  f32x4 v = *reinterpret_cast<const f32x4*>(in + i);
  bf16x4 o;
  o[0] = (bf16)v[0]; o[1] = (bf16)v[1]; o[2] = (bf16)v[2]; o[3] = (bf16)v[3];
  *reinterpret_cast<bf16x4*>(out + i) = o;
}

// ---------------- GEMM: C = A * BT^T + bias (unchanged, verified) ----------------
template<int EPI>
__global__ __launch_bounds__(256, 2)
void gemm_bt(const bf16* __restrict__ A, const bf16* __restrict__ BT,
             const float* __restrict__ bias, void* __restrict__ Cout,
             int M, int N, int K) {
  __shared__ bf16 As[128 * 64];
  __shared__ bf16 Bs[128 * 64];
  const int tid = threadIdx.x;
  const int lane = tid & 63;
  const int w = tid >> 6;
  const int wm = w >> 1, wn = w & 1;
  const int row0 = blockIdx.y * 128, col0 = blockIdx.x * 128;

  f32x4 acc[4][4] = {};

  const int srow = tid >> 3;
  const int scb = ((tid & 7) << 4) ^ ((srow & 7) << 4);
  const long aoff = (long)(row0 + srow) * K + (scb >> 1);
  const long boff = (long)(col0 + srow) * K + (scb >> 1);

  for (int k0 = 0; k0 < K; k0 += 64) {
    #pragma unroll
    for (int i = 0; i < 4; ++i) {
      __builtin_amdgcn_global_load_lds(AS1C(A + aoff + (long)i * 32 * K + k0),
                                       AS3((char*)As + i * 4096 + w * 1024), 16, 0, 0);
      __builtin_amdgcn_global_load_lds(AS1C(BT + boff + (long)i * 32 * K + k0),
                                       AS3((char*)Bs + i * 4096 + w * 1024), 16, 0, 0);
    }
    __syncthreads();
    #pragma unroll
    for (int kf = 0; kf < 2; ++kf) {
      bf16x8 af[4], bfr[4];
      #pragma unroll
      for (int m = 0; m < 4; ++m) {
        int r = wm * 64 + m * 16 + (lane & 15);
        int cb = (kf * 64 + ((lane >> 4) << 4)) ^ ((r & 7) << 4);
        af[m] = *reinterpret_cast<const bf16x8*>((const char*)As + r * 128 + cb);
      }
      #pragma unroll
      for (int n = 0; n < 4; ++n) {
        int r = wn * 64 + n * 16 + (lane & 15);
        int cb = (kf * 64 + ((lane >> 4) << 4)) ^ ((r & 7) << 4);
        bfr[n] = *reinterpret_cast<const bf16x8*>((const char*)Bs + r * 128 + cb);
      }
      #pragma unroll
      for (int m = 0; m < 4; ++m)
        #pragma unroll
        for (int n = 0; n < 4; ++n)
          acc[m][n] = __builtin_amdgcn_mfma_f32_16x16x32_bf16(af[m], bfr[n], acc[m][n], 0, 0, 0);
    }
    __syncthreads();
  }

  #pragma unroll
  for (int m = 0; m < 4; ++m) {
    #pragma unroll
    for (int n = 0; n < 4; ++n) {
      #pragma unroll
      for (int r = 0; r < 4; ++r) {
        int grow = row0 + wm * 64 + m * 16 + ((lane >> 4) << 2) + r;
        int gcol = col0 + wn * 64 + n * 16 + (lane & 15);
        float v = acc[m][n][r] + bias[gcol];
        if constexpr (EPI == 0) {
          reinterpret_cast<float*>(Cout)[(long)grow * N + gcol] = v;
        } else {
          int t = gcol >> 10;
          int h = (gcol >> 6) & 15;
          int hd = gcol & 63;
          int bb = grow >> 11;
          int ll = grow & 2047;
          long bh = bb * 16 + h;
          bf16* base = reinterpret_cast<bf16*>(Cout);
          if (t == 0) {
            base[(bh * 2048 + ll) * 64 + hd] = (bf16)(v * 0.125f);  // Q, scale folded
          } else if (t == 1) {
            base[8388608 + (bh * 2048 + ll) * 64 + hd] = (bf16)v;   // K
          } else {
            base[16777216 + (bh * 64 + hd) * 2048 + ll] = (bf16)v;  // V^T
          }
        }
      }
    }
  }
}

// ---------------- causal flash attention v3: swapped QK^T, in-register softmax --
// Q,K: [bh][2048][64] bf16 (Q pre-scaled). VT: [bh][64][2048] bf16.
// Grid: 2048 blocks (1D, XCD-chunk swizzled). Block: 4 waves x 16 q-rows.
// Per lane: one q-row (q = lane&15); S^T via mfma(K,Q); softmax in-register
// (in-lane tree + shfl_xor 16/32); PV via K=16 MFMA, P^T already in B-layout.
__global__ __launch_bounds__(256, 4)
void attn_fwd(const bf16* __restrict__ Qg, const bf16* __restrict__ Kg,
              const bf16* __restrict__ VTg, bf16* __restrict__ Og) {
  __shared__ bf16 Ks[2][64 * 64];
  __shared__ bf16 Vs[2][64 * 64];
  const int tid = threadIdx.x, lane = tid & 63, w = tid >> 6;
  const int g = lane >> 4, q = lane & 15;

  // XCD-chunked bijective swizzle: XCD x processes contiguous wgid chunk ->
  // 8 consecutive bh per XCD, qi descending (heavy first), K/V L2-resident.
  const int orig = blockIdx.x;
  const int wgid = (orig & 7) * 256 + (orig >> 3);
  const int bh = wgid >> 5;
  const int qi = 31 - (wgid & 31);
  const int bb = bh >> 4, h = bh & 15;
  const long base = (long)bh * (2048 * 64);
  const int qw = qi * 64 + w * 16;   // this wave's first q-row
  const int myq = qw + q;            // this lane's q-row

  // Q fragment (B-operand): B[j=q][k=d], d = g*8.. ; two 32-k halves
  bf16x8 qf[2];
  qf[0] = *reinterpret_cast<const bf16x8*>(Qg + base + (long)myq * 64 + g * 8);
  qf[1] = *reinterpret_cast<const bf16x8*>(Qg + base + (long)myq * 64 + 32 + g * 8);

  f32x4 accO[4] = {};                 // O^T: hd = 16*b + 4*g + r, col q
  float m = -1e30f, l = 0.f;

  const int srow = tid >> 3;
  const int scb = ((tid & 7) << 4) ^ ((srow & 7) << 4);
  const int nt = qi + 1;

  auto stage = [&](int kt, int buf) {
    #pragma unroll
    for (int i = 0; i < 2; ++i) {
      __builtin_amdgcn_global_load_lds(
          AS1C(Kg + base + (long)(kt * 64 + i * 32 + srow) * 64 + (scb >> 1)),
          AS3((char*)&Ks[buf][0] + i * 4096 + w * 1024), 16, 0, 0);
      __builtin_amdgcn_global_load_lds(
          AS1C(VTg + base + (long)(i * 32 + srow) * 2048 + kt * 64 + (scb >> 1)),
          AS3((char*)&Vs[buf][0] + i * 4096 + w * 1024), 16, 0, 0);
    }
  };

  stage(0, 0);

  for (int kt = 0; kt < nt; ++kt) {
    const int cur = kt & 1;
    __syncthreads();                          // stage(kt) complete
    if (kt + 1 < nt) stage(kt + 1, cur ^ 1);  // prefetch next tile

    const char* Kb = (const char*)&Ks[cur][0];
    const char* Vb = (const char*)&Vs[cur][0];

    // S^T[kv][q] = sum_d K[kv][d] Q[q][d]; lane owns q=lane&15, kv=a*16+4g+r
    f32x4 sT[4] = {};
    #pragma unroll
    for (int kf = 0; kf < 2; ++kf) {
      #pragma unroll
      for (int a = 0; a < 4; ++a) {
        int r = a * 16 + q;                                  // Ks row (A: i=lane&15)
        int cb = (kf * 64 + g * 16) ^ ((r & 7) << 4);
        bf16x8 kb = *reinterpret_cast<const bf16x8*>(Kb + r * 128 + cb);
        sT[a] = __builtin_amdgcn_mfma_f32_16x16x32_bf16(kb, qf[kf], sT[a], 0, 0, 0);
      }
    }

    // causal mask: only the diagonal tile
    if (kt == qi) {
      #pragma unroll
      for (int a = 0; a < 4; ++a)
        #pragma unroll
        for (int r = 0; r < 4; ++r) {
          int kv = kt * 64 + a * 16 + 4 * g + r;
          if (kv > myq) sT[a][r] = -1e30f;
        }
    }

    // online softmax: in-lane tree over 16 values + 2-step butterfly
    float vm = -1e30f;
    #pragma unroll
    for (int a = 0; a < 4; ++a)
      #pragma unroll
      for (int r = 0; r < 4; ++r) vm = fmaxf(vm, sT[a][r]);
    vm = fmaxf(vm, __shfl_xor(vm, 16));
    vm = fmaxf(vm, __shfl_xor(vm, 32));
    float mnew = fmaxf(m, vm);
    float fac = __expf(m - mnew);
    m = mnew;

    float ps = 0.f;
    bf16x4 pa[4];
    #pragma unroll
    for (int a = 0; a < 4; ++a)
      #pragma unroll
      for (int r = 0; r < 4; ++r) {
        float p = __expf(sT[a][r] - mnew);
        ps += p;
        pa[a][r] = (bf16)p;
      }
    ps += __shfl_xor(ps, 16);
    ps += __shfl_xor(ps, 32);
    l = l * fac + ps;
    #pragma unroll
    for (int b = 0; b < 4; ++b) accO[b] *= fac;

    // O^T += V^T * P^T  (A = VT frag, B = P^T frag already in-layout)
    #pragma unroll
    for (int a = 0; a < 4; ++a) {
      #pragma unroll
      for (int b = 0; b < 4; ++b) {
        int row = b * 16 + q;                                // VT row = hd (A: i=lane&15)
        int cb = (a * 32 + g * 8) ^ ((row & 7) << 4);
        bf16x4 vfrag = *reinterpret_cast<const bf16x4*>(Vb + row * 128 + cb);
        accO[b] = pv_mfma(vfrag, pa[a], accO[b]);
      }
    }
  }

  // epilogue: normalize, transpose O^T -> O through LDS (reuse Ks[0]), store coalesced
  __syncthreads();
  char* ob = (char*)&Ks[0][0] + w * 2048;   // 16 rows x 128B per wave
  float rl = 1.0f / l;
  #pragma unroll
  for (int b = 0; b < 4; ++b)
    #pragma unroll
    for (int r = 0; r < 4; ++r) {
      int hd = 16 * b + 4 * g + r;
      int cb = (hd * 2) ^ ((q & 7) << 4);
      *reinterpret_cast<bf16*>(ob + q * 128 + cb) = (bf16)(accO[b][r] * rl);
    }
  asm volatile("s_waitcnt lgkmcnt(0)" ::: "memory");
  __builtin_amdgcn_sched_barrier(0);

  const int rr = lane >> 2, cc = lane & 3;  // row 0..15, hd-chunk 0..3
  #pragma unroll
  for (int half = 0; half < 2; ++half) {
    int hd0 = cc * 16 + half * 8;
    int cb = (hd0 * 2) ^ ((rr & 7) << 4);
    bf16x8 vv = *reinterpret_cast<const bf16x8*>(ob + rr * 128 + cb);
    *reinterpret_cast<bf16x8*>(Og + (long)(bb * 2048 + qw + rr) * 1024 + h * 64 + hd0) = vv;
  }
}

// ---------------- launch ----------------
extern "C" void kernel_launch(void* const* d_in, const int* in_sizes, int n_in,
                              void* d_out, int out_size, void* d_ws, size_t ws_size,
                              hipStream_t stream) {
  (void)in_sizes; (void)n_in; (void)out_size; (void)ws_size;
  const float* x     = (const float*)d_in[0];
  const float* Wqkv  = (const float*)d_in[3];
  const float* bqkv  = (const float*)d_in[4];
  const float* Wproj = (const float*)d_in[5];
  const float* bproj = (const float*)d_in[6];

  bf16* xb     = (bf16*)d_ws;              // 8192*1024
  bf16* Wqkvb  = xb + 8388608;             // 3072*1024
  bf16* Wprojb = Wqkvb + 3145728;          // 1024*1024
  bf16* Qb     = Wprojb + 1048576;         // Q | K | VT : 3 * 8388608
  bf16* Ob     = Qb + 3 * 8388608;         // 8192*1024

  castk<<<8192, 256, 0, stream>>>(x, xb, 8388608);
  castk<<<3072, 256, 0, stream>>>(Wqkv, Wqkvb, 3145728);
  castk<<<1024, 256, 0, stream>>>(Wproj, Wprojb, 1048576);

  // QKV GEMM: M=8192, N=3072, K=1024, scatter epilogue
  gemm_bt<1><<<dim3(24, 64), 256, 0, stream>>>(xb, Wqkvb, bqkv, (void*)Qb, 8192, 3072, 1024);

  // attention: 2048 blocks (32 q-tiles x 64 bh), XCD-swizzled in-kernel
  attn_fwd<<<dim3(2048), 256, 0, stream>>>(Qb, Qb + 8388608, Qb + 16777216, Ob);

  // proj GEMM: M=8192, N=1024, K=1024 -> f32 d_out
  gemm_bt<0><<<dim3(8, 64), 256, 0, stream>>>(Ob, Wprojb, bproj, d_out, 8192, 1024, 1024);
}

// Round 4
// 196.443 us; speedup vs baseline: 1.5921x; 1.0262x over previous
//
#include <hip/hip_runtime.h>

typedef __bf16 bf16;
typedef __attribute__((ext_vector_type(8))) __bf16 bf16x8;
typedef __attribute__((ext_vector_type(4))) __bf16 bf16x4;
typedef __attribute__((ext_vector_type(4))) float f32x4;
typedef __attribute__((ext_vector_type(4))) short short4v;

#define AS1C(p) ((const __attribute__((address_space(1))) void*)(p))
#define AS3(p)  ((__attribute__((address_space(3))) void*)(p))

// K=16 bf16 MFMA for PV (P^T frag is already in B-layout: zero cross-lane movement)
static __device__ __forceinline__ f32x4 pv_mfma(bf16x4 a, bf16x4 b, f32x4 c) {
#if __has_builtin(__builtin_amdgcn_mfma_f32_16x16x16bf16_1k)
  return __builtin_amdgcn_mfma_f32_16x16x16bf16_1k(
      __builtin_bit_cast(short4v, a), __builtin_bit_cast(short4v, b), c, 0, 0, 0);
#else
  f32x4 d = c;
  asm("v_mfma_f32_16x16x16_bf16 %0, %1, %2, %0" : "+v"(d) : "v"(a), "v"(b));
  return d;
#endif
}

// ---------------- cast f32 -> bf16, vectorized ----------------
__global__ void castk(const float* __restrict__ in, bf16* __restrict__ out, long n) {
  long i = ((long)blockIdx.x * blockDim.x + threadIdx.x) * 4;
  if (i >= n) return;
  f32x4 v = *reinterpret_cast<const f32x4*>(in + i);
  bf16x4 o;
  o[0] = (bf16)v[0]; o[1] = (bf16)v[1]; o[2] = (bf16)v[2]; o[3] = (bf16)v[3];
  *reinterpret_cast<bf16x4*>(out + i) = o;
}

// ---------------- GEMM: C = A * BT^T + bias ----------------
// A [M][K] bf16 row-major, BT [N][K] bf16 row-major.
// MODE 0: proj -> f32 C[M][N] (+bias), original orientation.
// MODE 1: QK half of QKV. SWAPPED mfma operands so hd runs along the 4g+r axis:
//         each thread stores bf16x4 [bh][l][hd] chunks (Q scaled 0.125). grid.x=16.
// MODE 2: V half -> VT [bh][hd][2048]. Original orientation: ll runs along 4g+r,
//         bf16x4 stores along VT rows. Caller passes BT+2048*K, bias+2048, VT base.
template<int MODE>
__global__ __launch_bounds__(256, 2)
void gemm_bt(const bf16* __restrict__ A, const bf16* __restrict__ BT,
             const float* __restrict__ bias, void* __restrict__ Cout,
             int M, int N, int K) {
  __shared__ bf16 As[128 * 64];
  __shared__ bf16 Bs[128 * 64];
  const int tid = threadIdx.x;
  const int lane = tid & 63;
  const int w = tid >> 6;
  const int wm = w >> 1, wn = w & 1;
  const int row0 = blockIdx.y * 128, col0 = blockIdx.x * 128;

  f32x4 acc[4][4] = {};

  const int srow = tid >> 3;
  const int scb = ((tid & 7) << 4) ^ ((srow & 7) << 4);
  const long aoff = (long)(row0 + srow) * K + (scb >> 1);
  const long boff = (long)(col0 + srow) * K + (scb >> 1);

  for (int k0 = 0; k0 < K; k0 += 64) {
    #pragma unroll
    for (int i = 0; i < 4; ++i) {
      __builtin_amdgcn_global_load_lds(AS1C(A + aoff + (long)i * 32 * K + k0),
                                       AS3((char*)As + i * 4096 + w * 1024), 16, 0, 0);
      __builtin_amdgcn_global_load_lds(AS1C(BT + boff + (long)i * 32 * K + k0),
                                       AS3((char*)Bs + i * 4096 + w * 1024), 16, 0, 0);
    }
    __syncthreads();
    #pragma unroll
    for (int kf = 0; kf < 2; ++kf) {
      bf16x8 af[4], bfr[4];
      #pragma unroll
      for (int m = 0; m < 4; ++m) {
        int r = wm * 64 + m * 16 + (lane & 15);
        int cb = (kf * 64 + ((lane >> 4) << 4)) ^ ((r & 7) << 4);
        af[m] = *reinterpret_cast<const bf16x8*>((const char*)As + r * 128 + cb);
      }
      #pragma unroll
      for (int n = 0; n < 4; ++n) {
        int r = wn * 64 + n * 16 + (lane & 15);
        int cb = (kf * 64 + ((lane >> 4) << 4)) ^ ((r & 7) << 4);
        bfr[n] = *reinterpret_cast<const bf16x8*>((const char*)Bs + r * 128 + cb);
      }
      #pragma unroll
      for (int m = 0; m < 4; ++m)
        #pragma unroll
        for (int n = 0; n < 4; ++n) {
          if constexpr (MODE == 1)
            acc[m][n] = __builtin_amdgcn_mfma_f32_16x16x32_bf16(bfr[n], af[m], acc[m][n], 0, 0, 0);
          else
            acc[m][n] = __builtin_amdgcn_mfma_f32_16x16x32_bf16(af[m], bfr[n], acc[m][n], 0, 0, 0);
        }
    }
    __syncthreads();
  }

  const int g = lane >> 4, q = lane & 15;

  if constexpr (MODE == 0) {
    // C[grow][gcol], row=4g+r along grow, col=q along gcol
    #pragma unroll
    for (int m = 0; m < 4; ++m)
      #pragma unroll
      for (int n = 0; n < 4; ++n)
        #pragma unroll
        for (int r = 0; r < 4; ++r) {
          int grow = row0 + wm * 64 + m * 16 + g * 4 + r;
          int gcol = col0 + wn * 64 + n * 16 + q;
          reinterpret_cast<float*>(Cout)[(long)grow * N + gcol] = acc[m][n][r] + bias[gcol];
        }
  } else if constexpr (MODE == 1) {
    // swapped: value at gcol = col0+wn*64+n*16+4g+r, grow = row0+wm*64+m*16+q
    const int t = (int)blockIdx.x >> 3;                  // 0=Q, 1=K
    const int h = (((int)blockIdx.x << 1) | wn) & 15;
    const float qs = (t == 0) ? 0.125f : 1.0f;
    bf16* outb = reinterpret_cast<bf16*>(Cout) + (t ? 8388608 : 0);
    #pragma unroll
    for (int n = 0; n < 4; ++n) {
      f32x4 bv = *reinterpret_cast<const f32x4*>(bias + col0 + wn * 64 + n * 16 + g * 4);
      #pragma unroll
      for (int m = 0; m < 4; ++m) {
        int grow = row0 + wm * 64 + m * 16 + q;
        int bb = grow >> 11, ll = grow & 2047;
        bf16x4 o;
        #pragma unroll
        for (int r = 0; r < 4; ++r) o[r] = (bf16)((acc[m][n][r] + bv[r]) * qs);
        *reinterpret_cast<bf16x4*>(outb + ((long)(bb * 16 + h) * 2048 + ll) * 64 + n * 16 + g * 4) = o;
      }
    }
  } else {
    // MODE 2: original orientation; value at grow = row0+wm*64+m*16+4g+r (ll),
    // gcol_local = col0+wn*64+n*16+q -> hd = n*16+q. Cout = VT base.
    const int h = (((int)blockIdx.x << 1) | wn) & 15;
    bf16* outb = reinterpret_cast<bf16*>(Cout);
    #pragma unroll
    for (int n = 0; n < 4; ++n) {
      float bv = bias[col0 + wn * 64 + n * 16 + q];
      int hd = n * 16 + q;
      #pragma unroll
      for (int m = 0; m < 4; ++m) {
        int grow = row0 + wm * 64 + m * 16 + g * 4;
        int bb = grow >> 11, ll = grow & 2047;
        bf16x4 o;
        #pragma unroll
        for (int r = 0; r < 4; ++r) o[r] = (bf16)(acc[m][n][r] + bv);
        *reinterpret_cast<bf16x4*>(outb + ((long)(bb * 16 + h) * 64 + hd) * 2048 + ll) = o;
      }
    }
  }
}

// ---------------- causal flash attention v3 (unchanged from r3, verified) ------
__global__ __launch_bounds__(256, 4)
void attn_fwd(const bf16* __restrict__ Qg, const bf16* __restrict__ Kg,
              const bf16* __restrict__ VTg, bf16* __restrict__ Og) {
  __shared__ bf16 Ks[2][64 * 64];
  __shared__ bf16 Vs[2][64 * 64];
  const int tid = threadIdx.x, lane = tid & 63, w = tid >> 6;
  const int g = lane >> 4, q = lane & 15;

  const int orig = blockIdx.x;
  const int wgid = (orig & 7) * 256 + (orig >> 3);
  const int bh = wgid >> 5;
  const int qi = 31 - (wgid & 31);
  const int bb = bh >> 4, h = bh & 15;
  const long base = (long)bh * (2048 * 64);
  const int qw = qi * 64 + w * 16;
  const int myq = qw + q;

  bf16x8 qf[2];
  qf[0] = *reinterpret_cast<const bf16x8*>(Qg + base + (long)myq * 64 + g * 8);
  qf[1] = *reinterpret_cast<const bf16x8*>(Qg + base + (long)myq * 64 + 32 + g * 8);

  f32x4 accO[4] = {};
  float m = -1e30f, l = 0.f;

  const int srow = tid >> 3;
  const int scb = ((tid & 7) << 4) ^ ((srow & 7) << 4);
  const int nt = qi + 1;

  auto stage = [&](int kt, int buf) {
    #pragma unroll
    for (int i = 0; i < 2; ++i) {
      __builtin_amdgcn_global_load_lds(
          AS1C(Kg + base + (long)(kt * 64 + i * 32 + srow) * 64 + (scb >> 1)),
          AS3((char*)&Ks[buf][0] + i * 4096 + w * 1024), 16, 0, 0);
      __builtin_amdgcn_global_load_lds(
          AS1C(VTg + base + (long)(i * 32 + srow) * 2048 + kt * 64 + (scb >> 1)),
          AS3((char*)&Vs[buf][0] + i * 4096 + w * 1024), 16, 0, 0);
    }
  };

  stage(0, 0);

  for (int kt = 0; kt < nt; ++kt) {
    const int cur = kt & 1;
    __syncthreads();
    if (kt + 1 < nt) stage(kt + 1, cur ^ 1);

    const char* Kb = (const char*)&Ks[cur][0];
    const char* Vb = (const char*)&Vs[cur][0];

    f32x4 sT[4] = {};
    #pragma unroll
    for (int kf = 0; kf < 2; ++kf) {
      #pragma unroll
      for (int a = 0; a < 4; ++a) {
        int r = a * 16 + q;
        int cb = (kf * 64 + g * 16) ^ ((r & 7) << 4);
        bf16x8 kb = *reinterpret_cast<const bf16x8*>(Kb + r * 128 + cb);
        sT[a] = __builtin_amdgcn_mfma_f32_16x16x32_bf16(kb, qf[kf], sT[a], 0, 0, 0);
      }
    }

    if (kt == qi) {
      #pragma unroll
      for (int a = 0; a < 4; ++a)
        #pragma unroll
        for (int r = 0; r < 4; ++r) {
          int kv = kt * 64 + a * 16 + 4 * g + r;
          if (kv > myq) sT[a][r] = -1e30f;
        }
    }

    float vm = -1e30f;
    #pragma unroll
    for (int a = 0; a < 4; ++a)
      #pragma unroll
      for (int r = 0; r < 4; ++r) vm = fmaxf(vm, sT[a][r]);
    vm = fmaxf(vm, __shfl_xor(vm, 16));
    vm = fmaxf(vm, __shfl_xor(vm, 32));
    float mnew = fmaxf(m, vm);
    float fac = __expf(m - mnew);
    m = mnew;

    float ps = 0.f;
    bf16x4 pa[4];
    #pragma unroll
    for (int a = 0; a < 4; ++a)
      #pragma unroll
      for (int r = 0; r < 4; ++r) {
        float p = __expf(sT[a][r] - mnew);
        ps += p;
        pa[a][r] = (bf16)p;
      }
    ps += __shfl_xor(ps, 16);
    ps += __shfl_xor(ps, 32);
    l = l * fac + ps;
    #pragma unroll
    for (int b = 0; b < 4; ++b) accO[b] *= fac;

    #pragma unroll
    for (int a = 0; a < 4; ++a) {
      #pragma unroll
      for (int b = 0; b < 4; ++b) {
        int row = b * 16 + q;
        int cb = (a * 32 + g * 8) ^ ((row & 7) << 4);
        bf16x4 vfrag = *reinterpret_cast<const bf16x4*>(Vb + row * 128 + cb);
        accO[b] = pv_mfma(vfrag, pa[a], accO[b]);
      }
    }
  }

  __syncthreads();
  char* ob = (char*)&Ks[0][0] + w * 2048;
  float rl = 1.0f / l;
  #pragma unroll
  for (int b = 0; b < 4; ++b)
    #pragma unroll
    for (int r = 0; r < 4; ++r) {
      int hd = 16 * b + 4 * g + r;
      int cb = (hd * 2) ^ ((q & 7) << 4);
      *reinterpret_cast<bf16*>(ob + q * 128 + cb) = (bf16)(accO[b][r] * rl);
    }
  asm volatile("s_waitcnt lgkmcnt(0)" ::: "memory");
  __builtin_amdgcn_sched_barrier(0);

  const int rr = lane >> 2, cc = lane & 3;
  #pragma unroll
  for (int half = 0; half < 2; ++half) {
    int hd0 = cc * 16 + half * 8;
    int cb = (hd0 * 2) ^ ((rr & 7) << 4);
    bf16x8 vv = *reinterpret_cast<const bf16x8*>(ob + rr * 128 + cb);
    *reinterpret_cast<bf16x8*>(Og + (long)(bb * 2048 + qw + rr) * 1024 + h * 64 + hd0) = vv;
  }
}

// ---------------- launch ----------------
extern "C" void kernel_launch(void* const* d_in, const int* in_sizes, int n_in,
                              void* d_out, int out_size, void* d_ws, size_t ws_size,
                              hipStream_t stream) {
  (void)in_sizes; (void)n_in; (void)out_size; (void)ws_size;
  const float* x     = (const float*)d_in[0];
  const float* Wqkv  = (const float*)d_in[3];
  const float* bqkv  = (const float*)d_in[4];
  const float* Wproj = (const float*)d_in[5];
  const float* bproj = (const float*)d_in[6];

  bf16* xb     = (bf16*)d_ws;              // 8192*1024
  bf16* Wqkvb  = xb + 8388608;             // 3072*1024
  bf16* Wprojb = Wqkvb + 3145728;          // 1024*1024
  bf16* Qb     = Wprojb + 1048576;         // Q | K | VT : 3 * 8388608
  bf16* Ob     = Qb + 3 * 8388608;         // 8192*1024

  castk<<<8192, 256, 0, stream>>>(x, xb, 8388608);
  castk<<<3072, 256, 0, stream>>>(Wqkv, Wqkvb, 3145728);
  castk<<<1024, 256, 0, stream>>>(Wproj, Wprojb, 1048576);

  // QKV GEMM split: Q,K cols (swapped orientation) | V cols -> VT (original)
  gemm_bt<1><<<dim3(16, 64), 256, 0, stream>>>(xb, Wqkvb, bqkv, (void*)Qb, 8192, 3072, 1024);
  gemm_bt<2><<<dim3(8, 64), 256, 0, stream>>>(xb, Wqkvb + (long)2048 * 1024, bqkv + 2048,
                                              (void*)(Qb + 16777216), 8192, 3072, 1024);

  // attention: 2048 blocks (32 q-tiles x 64 bh), XCD-swizzled in-kernel
  attn_fwd<<<dim3(2048), 256, 0, stream>>>(Qb, Qb + 8388608, Qb + 16777216, Ob);

  // proj GEMM: M=8192, N=1024, K=1024 -> f32 d_out
  gemm_bt<0><<<dim3(8, 64), 256, 0, stream>>>(Ob, Wprojb, bproj, d_out, 8192, 1024, 1024);
}